// Round 5
// baseline (1204093.262 us; speedup 1.0000x reference)
//
#include <hip/hip_runtime.h>
#include <stdint.h>

#define T_STEPS 4096
#define BATCH 32
#define HID 512
#define GROUPS 8            // blocks per batch
#define BLK_THREADS 1024    // 16 waves/block; 256 blocks = 1/CU

typedef _Float16 h2_t __attribute__((ext_vector_type(2)));

__device__ inline uint32_t pack_h2(float a, float b) {
  h2_t v;
  v.x = (_Float16)a;
  v.y = (_Float16)b;
  return __builtin_bit_cast(uint32_t, v);
}

__device__ inline float fdot2(uint32_t a, uint32_t b, float c) {
  return __builtin_amdgcn_fdot2(__builtin_bit_cast(h2_t, a),
                                __builtin_bit_cast(h2_t, b), c, false);
}

// AGPR-resident weight read (unified RF; proven rounds 3-4).
__device__ inline uint32_t aread(uint32_t a) {
  uint32_t v;
  asm("v_accvgpr_read_b32 %0, %1" : "=v"(v) : "a"(a));
  return v;
}

__device__ inline float sigf(float x) { return 1.0f / (1.0f + __expf(-x)); }
__device__ inline float tanh_fast(float x) {
  float a = fabsf(x);
  float e = __expf(-2.0f * a);
  float r = (1.0f - e) / (1.0f + e);
  return copysignf(r, x);
}

// Round 5: BARRIER-FREE persistent LSTM. 256 blocks = 32 batches x 8 groups.
// Each WAVE autonomously owns 4 hidden units (16 gate-rows); lane l covers
// cols 8l..8l+7 of all 16 rows (64 weight dwords in AGPRs). Per step, per
// wave: poll own 8-unit-per-lane slice of this block's PRIVATE mailbox
// (tagged f16 dwords, tag=step => self-validating, double-buffered by step
// parity) -> strip/pack -> 64 fdot2 -> in-wave tree fold (xor1..8 fold
// 16 accs -> 1, then xor16/32): lane (l&15) holds row (l&15)'s full sum ->
// 3 shfl_xor gather the 4 gates to lanes (l&15)<4 -> activation -> one
// 32-lane store multicasts the 4 tagged h dwords to all 8 blocks' mailboxes.
// y accumulates via LDS atomics, drained after the t-loop. NO __syncthreads
// and NO cross-wave dependency inside the step loop: kills the barrier
// convoy amplification behind rounds 2-4's 2.7-3.5x run-to-run variance.
__global__ __launch_bounds__(BLK_THREADS)
void lstm_wavesync(const float* __restrict__ x0,
                   const float* __restrict__ W_ih,
                   const float* __restrict__ W_hh,
                   const float* __restrict__ b_ih,
                   const float* __restrict__ b_hh,
                   const float* __restrict__ W_lin,
                   const float* __restrict__ b_lin,
                   float* __restrict__ y,
                   uint32_t* __restrict__ h_ex)  // [2][BATCH][GROUPS][512]
{
  __shared__ float x0_lds[T_STEPS];   // 16 KB: this batch's x0 column
  __shared__ float ylds[T_STEPS];     // 16 KB: per-block y partials

  const int tid = threadIdx.x;
  // XCD-grouped mapping (perf heuristic only): batch's 8 groups share an XCD
  // if consecutive blockIdx round-robin across XCDs.
  const int xcd = blockIdx.x & 7;
  const int s   = blockIdx.x >> 3;
  const int g   = s & 7;                      // group within batch
  const int b   = xcd + 8 * (s >> 3);         // batch
  const int wv  = tid >> 6;                   // wave 0..15
  const int l   = tid & 63;
  const int u   = l & 3;                      // unit within wave (valid l&15<4)
  const int U   = 64 * g + 4 * wv + u;        // global hidden unit

  // ---- one-time: 16 rows x 8 cols of W_hh per lane, packed f16x2 -> AGPR ----
  uint32_t aw[64];
#pragma unroll
  for (int r = 0; r < 16; ++r) {
    const int R = (r >> 2) * HID + 64 * g + 4 * wv + (r & 3);  // gate*512+unit
    const float4* pr = (const float4*)(W_hh + (size_t)R * HID + 8 * l);
    float4 fa = pr[0], fb = pr[1];
    uint32_t t0 = pack_h2(fa.x, fa.y), t1 = pack_h2(fa.z, fa.w);
    uint32_t t2 = pack_h2(fb.x, fb.y), t3 = pack_h2(fb.z, fb.w);
    asm("v_accvgpr_write_b32 %0, %1" : "=a"(aw[4 * r + 0]) : "v"(t0));
    asm("v_accvgpr_write_b32 %0, %1" : "=a"(aw[4 * r + 1]) : "v"(t1));
    asm("v_accvgpr_write_b32 %0, %1" : "=a"(aw[4 * r + 2]) : "v"(t2));
    asm("v_accvgpr_write_b32 %0, %1" : "=a"(aw[4 * r + 3]) : "v"(t3));
  }

  // ---- one-time: x0 column + y accumulator init ----
  for (int i = tid; i < T_STEPS; i += BLK_THREADS) {
    x0_lds[i] = x0[i * BATCH + b];
    ylds[i] = 0.f;
  }

  // ---- per-lane activation constants (meaningful on lanes with l&15 < 4) ----
  float wih_[4], bs_[4];
#pragma unroll
  for (int j = 0; j < 4; ++j) {
    wih_[j] = W_ih[j * HID + U];
    bs_[j] = b_ih[j * HID + U] + b_hh[j * HID + U];
  }
  const float wlin_u = W_lin[U];
  const float blin = b_lin[0];
  float c_state = 0.f;

  // ---- mailbox pointers (both parity slots precomputed) ----
  // consumer: this block's private copy; lane l reads units 8l..8l+7 (4 u64)
  const uint64_t* cons[2];
  cons[0] = (const uint64_t*)(h_ex + (((size_t)0 * BATCH + b) * GROUPS + g) * HID) + 4 * l;
  cons[1] = (const uint64_t*)(h_ex + (((size_t)1 * BATCH + b) * GROUPS + g) * HID) + 4 * l;
  // producer: lanes 0..31 multicast unit (l&3) to target block tb = l>>2
  const int tb = (l >> 2) & 7;
  uint32_t* prod[2];
  prod[0] = h_ex + (((size_t)0 * BATCH + b) * GROUPS + tb) * HID + 64 * g + 4 * wv + u;
  prod[1] = h_ex + (((size_t)1 * BATCH + b) * GROUPS + tb) * HID + 64 * g + 4 * wv + u;

  __syncthreads();   // x0_lds/ylds ready; the LAST barrier before the drain

  int dead = 0;
  for (int t = 0; t < T_STEPS; ++t) {
    const int sl = t & 1;

    // ---- poll own slice: 4 x u64 atomic loads; min-tag >= t => all valid ----
    uint64_t v0, v1, v2, v3;
    {
      const uint64_t* cp = cons[sl];
      const uint32_t tg = (uint32_t)t;
      int guard = 0;
      for (;;) {
        v0 = __hip_atomic_load(cp + 0, __ATOMIC_RELAXED, __HIP_MEMORY_SCOPE_AGENT);
        v1 = __hip_atomic_load(cp + 1, __ATOMIC_RELAXED, __HIP_MEMORY_SCOPE_AGENT);
        v2 = __hip_atomic_load(cp + 2, __ATOMIC_RELAXED, __HIP_MEMORY_SCOPE_AGENT);
        v3 = __hip_atomic_load(cp + 3, __ATOMIC_RELAXED, __HIP_MEMORY_SCOPE_AGENT);
        uint32_t m0 = min(((uint32_t)v0) >> 16, (uint32_t)(v0 >> 48));
        uint32_t m1 = min(((uint32_t)v1) >> 16, (uint32_t)(v1 >> 48));
        uint32_t m2 = min(((uint32_t)v2) >> 16, (uint32_t)(v2 >> 48));
        uint32_t m3 = min(((uint32_t)v3) >> 16, (uint32_t)(v3 >> 48));
        uint32_t mn = min(min(m0, m1), min(m2, m3));
        if (__all((int)(mn >= tg))) break;
        if (dead || ++guard > (1 << 16)) { dead = 1; break; }  // no-hang guard
        __builtin_amdgcn_s_sleep(2);
      }
    }

    // ---- strip tags, pack h pairs: (h_odd<<16)|h_even via v_perm ----
    uint32_t ph0 = __builtin_amdgcn_perm((uint32_t)(v0 >> 32), (uint32_t)v0, 0x05040100u);
    uint32_t ph1 = __builtin_amdgcn_perm((uint32_t)(v1 >> 32), (uint32_t)v1, 0x05040100u);
    uint32_t ph2 = __builtin_amdgcn_perm((uint32_t)(v2 >> 32), (uint32_t)v2, 0x05040100u);
    uint32_t ph3 = __builtin_amdgcn_perm((uint32_t)(v3 >> 32), (uint32_t)v3, 0x05040100u);

    // ---- matvec: 16 rows x 8 cols per lane ----
    float a_[16];
#pragma unroll
    for (int r = 0; r < 16; ++r) {
      float acc = fdot2(aread(aw[4 * r + 0]), ph0, 0.f);
      acc = fdot2(aread(aw[4 * r + 1]), ph1, acc);
      acc = fdot2(aread(aw[4 * r + 2]), ph2, acc);
      acc = fdot2(aread(aw[4 * r + 3]), ph3, acc);
      a_[r] = acc;
    }

    // ---- in-wave tree fold: after level k, a_[i] holds rows with low bits
    // matching lane's low bits; end: lane (l&15) has row (l&15) partial ----
#pragma unroll
    for (int k = 0; k < 4; ++k) {
      const int bit = (l >> k) & 1;
#pragma unroll
      for (int i = 0; i < (8 >> k); ++i) {
        float sv = bit ? a_[2 * i] : a_[2 * i + 1];     // send partner's keep
        float rv = __shfl_xor(sv, 1 << k, 64);
        a_[i] = (bit ? a_[2 * i + 1] : a_[2 * i]) + rv;
      }
    }
    float acc = a_[0];
    acc += __shfl_xor(acc, 16, 64);   // fold remaining col groups
    acc += __shfl_xor(acc, 32, 64);   // lane l: row (l&15) full dot product

    // ---- gather 4 gates to unit lanes; activation (valid where l&15 < 4) ----
    float gi = acc;
    float gf = __shfl_xor(acc, 4, 64);
    float gg = __shfl_xor(acc, 8, 64);
    float go = __shfl_xor(acc, 12, 64);
    const float xv = x0_lds[t];
    gi += xv * wih_[0] + bs_[0];
    gf += xv * wih_[1] + bs_[1];
    gg += xv * wih_[2] + bs_[2];
    go += xv * wih_[3] + bs_[3];
    float si = sigf(gi), sf = sigf(gf), tg_ = tanh_fast(gg), so = sigf(go);
    c_state = sf * c_state + si * tg_;
    float h = so * tanh_fast(c_state);

    // ---- publish FIRST: one 32-lane store = 8-block multicast of 4 units ----
    uint16_t hb = __builtin_bit_cast(uint16_t, (_Float16)h);
    uint32_t tagged = ((uint32_t)(t + 1) << 16) | (uint32_t)hb;
    uint32_t ts = __shfl(tagged, u, 64);   // pull unit (l&3)'s value (lanes 0-3)
    if (l < 32) {
      __hip_atomic_store(prod[sl ^ 1], ts, __ATOMIC_RELAXED,
                         __HIP_MEMORY_SCOPE_AGENT);
    }

    // ---- y partial: fold this wave's 4 units, one LDS atomic (off path) ----
    float p = wlin_u * h;
    p += __shfl_xor(p, 1, 64);
    p += __shfl_xor(p, 2, 64);
    if (l == 0) atomicAdd(&ylds[t], p);
  }

  // ---- drain: block partials -> global (bias + residual added by g==0) ----
  __syncthreads();
  for (int i = tid; i < T_STEPS; i += BLK_THREADS) {
    float val = ylds[i];
    if (g == 0) val += blin + x0_lds[i];
    unsafeAtomicAdd(&y[i * BATCH + b], val);
  }
}

extern "C" void kernel_launch(void* const* d_in, const int* in_sizes, int n_in,
                              void* d_out, int out_size, void* d_ws, size_t ws_size,
                              hipStream_t stream) {
  const float* x0    = (const float*)d_in[0];
  const float* W_ih  = (const float*)d_in[1];
  const float* W_hh  = (const float*)d_in[2];
  const float* b_ih  = (const float*)d_in[3];
  const float* b_hh  = (const float*)d_in[4];
  const float* W_lin = (const float*)d_in[5];
  const float* b_lin = (const float*)d_in[6];
  float* y = (float*)d_out;

  uint32_t* h_ex = (uint32_t*)d_ws;  // [2][32][8][512] u32 = 1 MB
  const size_t init_bytes = (size_t)2 * BATCH * GROUPS * HID * sizeof(uint32_t);

  // memset 0 => slot-0 tags = 0 with h = 0.0f16: exactly the h0 = 0 state.
  hipMemsetAsync(d_ws, 0, init_bytes, stream);
  hipMemsetAsync(d_out, 0, (size_t)out_size * sizeof(float), stream);

  hipLaunchKernelGGL(lstm_wavesync, dim3(BATCH * GROUPS), dim3(BLK_THREADS),
                     0, stream,
                     x0, W_ih, W_hh, b_ih, b_hh, W_lin, b_lin, y, h_ex);
}

// Round 6
// 28464.389 us; speedup vs baseline: 42.3017x; 42.3017x over previous
//
#include <hip/hip_runtime.h>
#include <stdint.h>

#define T_STEPS 4096
#define BATCH 32
#define HID 512
#define GROUPS 8            // blocks per batch
#define BLK_THREADS 1024    // 16 waves; 256 blocks = exactly 1/CU
#define NBLOCKS 256

typedef _Float16 h2_t __attribute__((ext_vector_type(2)));

__device__ inline uint32_t pack_h2(float a, float b) {
  h2_t v;
  v.x = (_Float16)a;
  v.y = (_Float16)b;
  return __builtin_bit_cast(uint32_t, v);
}

__device__ inline float fdot2(uint32_t a, uint32_t b, float c) {
  return __builtin_amdgcn_fdot2(__builtin_bit_cast(h2_t, a),
                                __builtin_bit_cast(h2_t, b), c, false);
}

// AGPR-resident weight read (unified RF; proven rounds 3-4 to keep W_hh
// on-chip across the whole t-loop).
__device__ inline uint32_t aread(uint32_t a) {
  uint32_t v;
  asm("v_accvgpr_read_b32 %0, %1" : "=v"(v) : "a"(a));
  return v;
}

// L2-scope communication (gfx950): sc0 loads bypass the per-CU L1 and are
// served by the XCD's L2 — the valid coherence point for blocks that are
// GUARANTEED same-XCD (see claim protocol below). ~85 ns vs ~500-900 ns for
// agent-scope/MALL (sc0+sc1) ops — the round-2..5 critical-path cost.
__device__ inline uint32_t l2_load(const uint32_t* p) {
  uint32_t v;
  asm volatile("global_load_dword %0, %1, off sc0\n\ts_waitcnt vmcnt(0)"
               : "=v"(v) : "v"(p) : "memory");
  return v;
}
__device__ inline void l2_store(uint32_t* p, uint32_t v) {
  asm volatile("global_store_dword %0, %1, off sc0" :: "v"(p), "v"(v)
               : "memory");
}

__device__ inline float sigf(float x) { return 1.0f / (1.0f + __expf(-x)); }
__device__ inline float tanh_fast(float x) {
  float a = fabsf(x);
  float e = __expf(-2.0f * a);
  float r = (1.0f - e) / (1.0f + e);
  return copysignf(r, x);
}

// Round 6 = round 4's proven structure (tagged self-validating h, one
// barrier/step, AGPR weights) + XCD-local communication:
//
// PLACEMENT BY SELF-SELECTION: 256 blocks (1/CU). Each block reads its
// physical XCC_ID and claims a slot from a per-XCD counter: 32 slots/XCD =
// 4 batches x 8 groups, matching the 32 CUs/XCD exactly. So all 8 groups of
// a batch are same-XCD BY CONSTRUCTION (not by dispatch-order assumption),
// making sc0/L2 coherence valid for the h exchange. Claim is one-time,
// agent-scope. Surplus blocks (if any) exit immediately.
//
// Round-5 post-mortem (1.2 s): wave-autonomous agent-scope mailboxes
// saturate the MALL with L2-bypassing polls — never again. All per-step
// traffic here stays inside one XCD's L2.
__global__ __launch_bounds__(BLK_THREADS)
void lstm_xcd(const float* __restrict__ x0,
              const float* __restrict__ W_ih,
              const float* __restrict__ W_hh,
              const float* __restrict__ b_ih,
              const float* __restrict__ b_hh,
              const float* __restrict__ W_lin,
              const float* __restrict__ b_lin,
              float* __restrict__ y,
              uint32_t* __restrict__ h_ex,   // [BATCH][2][512] tagged f16
              int* __restrict__ claim)       // [8][16] per-XCD counters
{
  __shared__ float x0_lds[T_STEPS];     // 16 KB: this batch's x0 column
  __shared__ float ylds[T_STEPS];       // 16 KB: per-block y partials
  __shared__ uint32_t trans[16][32];    // per-wave f16x2 transpose
  __shared__ float gacc[2][256];        // parity-buffered gate accumulators
  __shared__ int s_bg;

  const int tid = threadIdx.x;

  // ---- claim a (batch, group) slot on THIS block's physical XCD ----
  if (tid == 0) {
    uint32_t xcc;
    asm volatile("s_getreg_b32 %0, hwreg(HW_REG_XCC_ID)" : "=s"(xcc));
    xcc &= 7;
    int slot = atomicAdd(claim + xcc * 16, 1);   // agent-scope, one-time
    s_bg = (slot < 32) ? (int)(((4 * xcc + (slot >> 3)) << 3) | (slot & 7))
                       : -1;
  }
  __syncthreads();
  if (s_bg < 0) return;                  // surplus block
  const int b  = s_bg >> 3;              // batch (same XCD for all 8 groups)
  const int g  = s_bg & 7;               // group within batch
  const int u0 = g * 64;                 // first hidden unit owned
  const int wv = tid >> 6;               // wave 0..15
  const int rg = wv >> 3;                // row-group 0..1
  const int cs = wv & 7;                 // col-slice 0..7 (64 cols)
  const int l  = tid & 63;

  // ---- one-time: W_hh slice -> packed f16x2 -> AGPRs (round-4 layout) ----
  uint32_t a0[32], a1[32];
  {
    const int r0 = 128 * rg + l;
    const int r1 = r0 + 64;
    const int R0 = (r0 >> 6) * HID + u0 + (r0 & 63);  // gate*512 + unit
    const int R1 = (r1 >> 6) * HID + u0 + (r1 & 63);
    const float2* p0 = (const float2*)(W_hh + (size_t)R0 * HID + 64 * cs);
    const float2* p1 = (const float2*)(W_hh + (size_t)R1 * HID + 64 * cs);
#pragma unroll
    for (int k = 0; k < 32; ++k) {
      float2 a = p0[k], c = p1[k];
      uint32_t t0 = pack_h2(a.x, a.y);
      uint32_t t1 = pack_h2(c.x, c.y);
      asm("v_accvgpr_write_b32 %0, %1" : "=a"(a0[k]) : "v"(t0));
      asm("v_accvgpr_write_b32 %0, %1" : "=a"(a1[k]) : "v"(t1));
    }
  }
  // ---- one-time: x0 column, y partials, gacc ----
  for (int i = tid; i < T_STEPS; i += BLK_THREADS) {
    x0_lds[i] = x0[i * BATCH + b];
    ylds[i] = 0.f;
  }
  if (tid < 256) { gacc[0][tid] = 0.f; gacc[1][tid] = 0.f; }

  // ---- activation-lane constants (lanes 0..63 of wave 0) ----
  float c_state = 0.f;
  float wih_[4] = {0.f, 0.f, 0.f, 0.f}, bs_[4] = {0.f, 0.f, 0.f, 0.f};
  float wlin_u = 0.f, blin = 0.f;
  if (tid < 64) {
#pragma unroll
    for (int j = 0; j < 4; ++j) {
      int R = j * HID + u0 + tid;
      wih_[j] = W_ih[R];
      bs_[j] = b_ih[R] + b_hh[R];
    }
    wlin_u = W_lin[u0 + tid];
    blin = b_lin[0];
  }

  // ---- per-batch exchange buffer, both parity slots ----
  uint32_t* hb = h_ex + (size_t)b * 1024;
  const uint32_t* src01[2] = { hb + 64 * cs + l, hb + 512 + 64 * cs + l };
  uint32_t* dst01[2] = { hb + u0 + tid, hb + 512 + u0 + tid };  // tid<64 only

  __syncthreads();

  int dead = 0;
  for (int t = 0; t < T_STEPS; ++t) {
    const int sl = t & 1, ns = sl ^ 1;

    // ---- poll own 64-dword column slice in L2; tag==t => valid ----
    uint32_t v;
    {
      const uint32_t* sp = src01[sl];
      int guard = 0;
      for (;;) {
        v = l2_load(sp);
        if (__all((int)((v >> 16) == (uint32_t)t))) break;
        if (dead || ++guard > (1 << 17)) { dead = 1; break; }  // anti-hang
      }
    }

    // zero the OTHER parity gacc for step t+1 (ordered by barrier below;
    // safe: our own activation already consumed gacc[ns] — round-4 proven)
    if (l < 16) gacc[ns][wv * 16 + l] = 0.f;

    // ---- wave-local transpose: tagged dwords -> packed f16x2 ----
    {
      uint32_t nv = __shfl_down(v, 1, 64);
      if ((l & 1) == 0) trans[wv][l >> 1] = (v & 0xffffu) | (nv << 16);
    }
    // ---- matvec: 2 rows x 64 cols per lane, fp32 accumulate ----
    float acc0 = 0.f, acc1 = 0.f;
    const uint4* hp = (const uint4*)trans[wv];   // wave-uniform broadcast
#pragma unroll
    for (int q = 0; q < 8; ++q) {
      uint4 h4 = hp[q];
      const int k = 4 * q;
      acc0 = fdot2(aread(a0[k + 0]), h4.x, acc0); acc1 = fdot2(aread(a1[k + 0]), h4.x, acc1);
      acc0 = fdot2(aread(a0[k + 1]), h4.y, acc0); acc1 = fdot2(aread(a1[k + 1]), h4.y, acc1);
      acc0 = fdot2(aread(a0[k + 2]), h4.z, acc0); acc1 = fdot2(aread(a1[k + 2]), h4.z, acc1);
      acc0 = fdot2(aread(a0[k + 3]), h4.w, acc0); acc1 = fdot2(aread(a1[k + 3]), h4.w, acc1);
    }
    atomicAdd(&gacc[sl][128 * rg + l], acc0);       // 2-way bank, conflict-free
    atomicAdd(&gacc[sl][128 * rg + 64 + l], acc1);
    __syncthreads();   // the ONE block barrier per step

    // ---- activations + publish + y (wave 0, 64 lanes = 64 owned units) ----
    if (tid < 64) {
      const float xv = x0_lds[t];
      float gi = gacc[sl][tid]       + xv * wih_[0] + bs_[0];
      float gf = gacc[sl][tid + 64]  + xv * wih_[1] + bs_[1];
      float gg = gacc[sl][tid + 128] + xv * wih_[2] + bs_[2];
      float go = gacc[sl][tid + 192] + xv * wih_[3] + bs_[3];
      float si = sigf(gi), sf = sigf(gf), tg_ = tanh_fast(gg), so = sigf(go);
      c_state = sf * c_state + si * tg_;
      float h = so * tanh_fast(c_state);

      // publish FIRST: tagged dword into the XCD's L2, no drain needed
      uint16_t hbb = __builtin_bit_cast(uint16_t, (_Float16)h);
      l2_store(dst01[ns], ((uint32_t)(t + 1) << 16) | (uint32_t)hbb);

      // y partial (off critical path): fold 64 units, store to LDS
      float p = wlin_u * h;
#pragma unroll
      for (int m = 32; m >= 1; m >>= 1) p += __shfl_xor(p, m, 64);
      if (tid == 0) ylds[t] = p;
    }
  }

  // ---- drain: block partials -> global y (g==0 adds bias + residual) ----
  __syncthreads();
  for (int i = tid; i < T_STEPS; i += BLK_THREADS) {
    float val = ylds[i];
    if (g == 0) val += blin + x0_lds[i];
    unsafeAtomicAdd(&y[i * BATCH + b], val);
  }
}

extern "C" void kernel_launch(void* const* d_in, const int* in_sizes, int n_in,
                              void* d_out, int out_size, void* d_ws, size_t ws_size,
                              hipStream_t stream) {
  const float* x0    = (const float*)d_in[0];
  const float* W_ih  = (const float*)d_in[1];
  const float* W_hh  = (const float*)d_in[2];
  const float* b_ih  = (const float*)d_in[3];
  const float* b_hh  = (const float*)d_in[4];
  const float* W_lin = (const float*)d_in[5];
  const float* b_lin = (const float*)d_in[6];
  float* y = (float*)d_out;

  uint32_t* h_ex = (uint32_t*)d_ws;                   // [32][2][512] = 128 KB
  int* claim = (int*)((char*)d_ws + (size_t)BATCH * 1024 * sizeof(uint32_t));
  const size_t init_bytes =
      (size_t)BATCH * 1024 * sizeof(uint32_t) + 8 * 16 * sizeof(int);

  // memset 0: slot-0 tags = 0 with h = 0.0f16 == the h0 = 0 state; claim = 0
  hipMemsetAsync(d_ws, 0, init_bytes, stream);
  hipMemsetAsync(d_out, 0, (size_t)out_size * sizeof(float), stream);

  hipLaunchKernelGGL(lstm_xcd, dim3(NBLOCKS), dim3(BLK_THREADS), 0, stream,
                     x0, W_ih, W_hh, b_ih, b_hh, W_lin, b_lin, y, h_ex, claim);
}